// Round 4
// baseline (8699.226 us; speedup 1.0000x reference)
//
#include <hip/hip_runtime.h>
#include <hip/hip_fp16.h>

// GInvariantLSTMLayer persistent-RNN, round 4.
// (1) Block's 1-KB h output aggregated via LDS transpose -> wave0 stores 16 B/lane
//     (two 8-B write-through stores): 32x fewer store transactions than 2-B scatter.
// (2) h loads are plain cached global_load_dwordx4 (XCD-L2 served); freshness from
//     ONE agent-acquire fence (L1+L2 inv) per block per step + 4-deep h rotation.

typedef _Float16 f16x8 __attribute__((ext_vector_type(8)));
typedef float    f32x4 __attribute__((ext_vector_type(4)));
typedef unsigned long long u64;

#define LROW 2056
#define NBLK 256u

static __device__ __forceinline__ float fast_sig(float x) {
  return 1.f / (1.f + __expf(-x));
}
static __device__ __forceinline__ float fast_tanh(float x) {
  x = fminf(15.f, fmaxf(-15.f, x));
  const float e = __expf(2.f * x);
  return (e - 1.f) / (e + 1.f);
}

static __device__ __forceinline__ void st_h16(void* p, float v) {
  const unsigned short b = __builtin_bit_cast(unsigned short, (_Float16)v);
  __hip_atomic_store((unsigned short*)p, b, __ATOMIC_RELAXED, __HIP_MEMORY_SCOPE_AGENT);
}
static __device__ __forceinline__ void st_h64(void* p, u64 v) {
  __hip_atomic_store((u64*)p, v, __ATOMIC_RELAXED, __HIP_MEMORY_SCOPE_AGENT);
}

// Packed h layout: element (n, j) at byte offset
//   ((n>>4)<<16) + ((j>>5)<<10) + ((n&15)<<6) + (((j>>3)&3)<<4) + ((j&7)<<1)
static __device__ __forceinline__ int h_off(int n, int j) {
  return ((n >> 4) << 16) + ((j >> 5) << 10) + ((n & 15) << 6) +
         (((j >> 3) & 3) << 4) + ((j & 7) << 1);
}

__global__ void __launch_bounds__(256) seq_sum_kernel(const float* __restrict__ X,
                                                      float* s_all) {
  const int gw   = (int)((blockIdx.x * blockDim.x + threadIdx.x) >> 6);
  const int lane = threadIdx.x & 63;
  const int n = gw >> 9, t = gw & 511;
  const float4* p = (const float4*)(X + ((size_t)gw << 10));
  float s = 0.f;
#pragma unroll
  for (int i = 0; i < 4; ++i) {
    const float4 v = p[lane + (i << 6)];
    s += (v.x + v.y) + (v.z + v.w);
  }
#pragma unroll
  for (int off = 32; off; off >>= 1) s += __shfl_xor(s, off);
  if (lane == 0) s_all[(t << 6) + n] = s;
}

__global__ void bar_init_kernel(unsigned* bar) {
  bar[threadIdx.x]       = 0u;
  bar[threadIdx.x + 256] = 0u;
  bar[threadIdx.x + 512] = 0u;
  bar[threadIdx.x + 768] = 0u;
}

static __device__ __forceinline__ void grid_barrier2(unsigned* bar, unsigned round,
                                                     int tid, int blk) {
  asm volatile("s_waitcnt vmcnt(0)" ::: "memory");
  __syncthreads();
  if (tid == 0) {
    unsigned* grp  = bar + ((blk & 7) << 5);
    unsigned* root = bar + 512;
    const unsigned old =
        __hip_atomic_fetch_add(grp, 1u, __ATOMIC_RELAXED, __HIP_MEMORY_SCOPE_AGENT);
    if (old == 32u * round - 1u)
      __hip_atomic_fetch_add(root, 1u, __ATOMIC_RELAXED, __HIP_MEMORY_SCOPE_AGENT);
    const unsigned target = 8u * round;
    unsigned guard = 0;
    while (__hip_atomic_load(root, __ATOMIC_RELAXED, __HIP_MEMORY_SCOPE_AGENT) <
           target) {
      __builtin_amdgcn_s_sleep(1);
      if (++guard > (1u << 23)) break;
    }
  }
  __syncthreads();
}

__global__ void __launch_bounds__(256) ginv_lstm_persist(
    const float* __restrict__ lin_W, const float* __restrict__ inv_w,
    const float* __restrict__ inv_b, const float* __restrict__ lin_b,
    const float* s_all, const float* __restrict__ H0,
    _Float16* hb0, _Float16* hb1, _Float16* hb2, _Float16* hb3,
    unsigned* bar, float* out) {
  __shared__ _Float16 Wl[32 * LROW];            // 131584 B
  __shared__ __align__(16) _Float16 hx[64][8];  // 1 KB transpose buffer
  const int blk = blockIdx.x;
  const int tid = threadIdx.x;
  _Float16* hbuf[4] = {hb0, hb1, hb2, hb3};

  for (int base = tid * 4; base < 32 * 2048; base += 1024) {
    const int r  = base >> 11;
    const int hc = base & 2047;
    const int g  = r >> 3;
    const int kf = r & 7;
    const float4 v =
        *(const float4*)&lin_W[(((size_t)(g * 2048 + blk * 8 + kf)) << 11) + hc];
    _Float16* d = &Wl[r * LROW + hc];
    d[0] = (_Float16)v.x; d[1] = (_Float16)v.y;
    d[2] = (_Float16)v.z; d[3] = (_Float16)v.w;
  }

  {
    int i0 = blk * 512 + tid;
    st_h16((char*)hb0 + h_off(i0 >> 11, i0 & 2047), H0[i0]);
    i0 += 256;
    st_h16((char*)hb0 + h_off(i0 >> 11, i0 & 2047), H0[i0]);
  }

  const int wave = tid >> 6;
  const int lane = tid & 63;
  const int q    = lane >> 4;
  const int cc   = lane & 15;
  const int kf   = cc & 7;
  const int Kg   = blk * 8 + kf;
  const int g0   = (cc < 8) ? 0 : 1;
  const int g1   = (cc < 8) ? 2 : 3;
  const float w0 = inv_w[(g0 << 11) + Kg];
  const float b0 = inv_b[(g0 << 11) + Kg] + lin_b[(g0 << 11) + Kg];
  const float w1 = inv_w[(g1 << 11) + Kg];
  const float b1 = inv_b[(g1 << 11) + Kg] + lin_b[(g1 << 11) + Kg];

  unsigned round = 1;
  grid_barrier2(bar, round, tid, blk);

  float cst[4] = {0.f, 0.f, 0.f, 0.f};

  const int ld_base = (wave << 16) + (cc << 6) + (q << 4);
  const int lb0 = cc * LROW + q * 8;
  const int lb1 = (16 + cc) * LROW + q * 8;
  const int st_off = ((lane >> 4) << 16) + ((blk >> 2) << 10) + ((lane & 15) << 6) +
                     ((blk & 3) << 4);

  for (int t = 0; t < 512; ++t) {
    // One agent-acquire per block: wave0's fence invalidates this CU's L1 and the
    // XCD's L2; h(t) is at the L3 coherence point (write-through + pre-release
    // vmcnt drain), so the plain cached loads below are fresh.
    if (tid < 64) __builtin_amdgcn_fence(__ATOMIC_ACQUIRE, "agent");
    __syncthreads();

    const char* hpb = (const char*)hbuf[t & 3] + ld_base;

    f32x4 acc0 = {0.f, 0.f, 0.f, 0.f};
    f32x4 acc1 = {0.f, 0.f, 0.f, 0.f};
#pragma unroll 8
    for (int kc = 0; kc < 64; ++kc) {
      const f16x8 a   = *(const f16x8*)(hpb + (kc << 10));   // global_load_dwordx4
      const f16x8 bb0 = *(const f16x8*)&Wl[lb0 + kc * 32];
      const f16x8 bb1 = *(const f16x8*)&Wl[lb1 + kc * 32];
      acc0 = __builtin_amdgcn_mfma_f32_16x16x32_f16(a, bb0, acc0, 0, 0, 0);
      acc1 = __builtin_amdgcn_mfma_f32_16x16x32_f16(a, bb1, acc1, 0, 0, 0);
    }

    const float4 s4 = *(const float4*)&s_all[(t << 6) + wave * 16 + q * 4];
    const float sv[4] = {s4.x, s4.y, s4.z, s4.w};
    float hnew[4];
#pragma unroll
    for (int v = 0; v < 4; ++v) {
      const float z0 = acc0[v] + sv[v] * w0 + b0;
      const float z1 = acc1[v] + sv[v] * w1 + b1;
      const float zf = __shfl_xor(z0, 8);
      const float zo = __shfl_xor(z1, 8);
      const float ig = fast_sig(z0);
      const float fg = fast_sig(zf);
      const float gg = fast_tanh(z1);
      const float og = fast_sig(zo);
      const float cn = fg * cst[v] + ig * gg;
      cst[v] = cn;
      hnew[v] = og * fast_tanh(cn);
    }

    // Transpose block's h slice through LDS (also at t=511, for the epilogue).
    if (cc < 8) {
#pragma unroll
      for (int v = 0; v < 4; ++v)
        hx[(wave << 4) + (q << 2) + v][cc] = (_Float16)hnew[v];
    }
    __syncthreads();
    if (t < 511 && tid < 64) {
      union { f16x8 v; u64 w[2]; } u;
      u.v = *(const f16x8*)hx[lane];
      char* dst = (char*)hbuf[(t + 1) & 3] + st_off;
      st_h64(dst, u.w[0]);
      st_h64(dst + 8, u.w[1]);
    }
    ++round;
    grid_barrier2(bar, round, tid, blk);   // also orders s_all reads vs out (fallback)
  }

  // Epilogue: hx holds h(511); lane = batch row, features blk*8..blk*8+7.
  if (tid < 64) {
    const f16x8 hv = *(const f16x8*)hx[lane];
#pragma unroll
    for (int f = 0; f < 8; ++f)
      out[((blk * 8 + f) << 6) + lane] = (float)hv[f];
  }
}

extern "C" void kernel_launch(void* const* d_in, const int* in_sizes, int n_in,
                              void* d_out, int out_size, void* d_ws, size_t ws_size,
                              hipStream_t stream) {
  const float* X     = (const float*)d_in[0];
  const float* H0    = (const float*)d_in[1];
  const float* inv_w = (const float*)d_in[2];
  const float* inv_b = (const float*)d_in[3];
  const float* lin_W = (const float*)d_in[4];
  const float* lin_b = (const float*)d_in[5];
  float* out = (float*)d_out;

  const size_t S_BYTES = 512 * 64 * 4;
  const size_t BAR_PAD = 4096;
  const size_t H_BYTES = 64 * 2048 * 2;
  const size_t NEED = S_BYTES + BAR_PAD + 4 * H_BYTES;

  float*    s_all;
  unsigned* bar;
  _Float16* hb[4];
  if (ws_size >= NEED) {
    char* ws = (char*)d_ws;
    s_all = (float*)ws;
    bar   = (unsigned*)(ws + S_BYTES);
    for (int i = 0; i < 4; ++i)
      hb[i] = (_Float16*)(ws + S_BYTES + BAR_PAD + (size_t)i * H_BYTES);
  } else {
    s_all = (float*)d_out;
    char* xt = (char*)d_in[0] + (size_t)64 * 512 * 1024 * 4 -
               (BAR_PAD + 4 * H_BYTES);
    bar = (unsigned*)xt;
    for (int i = 0; i < 4; ++i)
      hb[i] = (_Float16*)(xt + BAR_PAD + (size_t)i * H_BYTES);
  }

  seq_sum_kernel<<<8192, 256, 0, stream>>>(X, s_all);
  bar_init_kernel<<<1, 256, 0, stream>>>(bar);
  ginv_lstm_persist<<<256, 256, 0, stream>>>(lin_W, inv_w, inv_b, lin_b, s_all, H0,
                                             hb[0], hb[1], hb[2], hb[3], bar, out);
}

// Round 6
// 4352.744 us; speedup vs baseline: 1.9986x; 1.9986x over previous
//
#include <hip/hip_runtime.h>
#include <hip/hip_fp16.h>

// GInvariantLSTMLayer persistent-RNN, round 6.
// Backbone (r3, validated): sc1 cache-bypass loads + sc1 write-through stores, ZERO
// fences (r2/r4: any L2-invalidate scheme loses). r5's all-64 asm prefetch NaN'd
// (address-reg explosion -> spills of unlanded asm outputs + missing memory clobbers
// on waits). r6: bounded 2-deep x 16-fragment pipeline, 32 loads in flight max,
// 4 address pairs per group (imm offsets), memory-clobbered vmcnt waits, s_all read
// issued BEFORE the pipeline (older outstanding ops only make waits stricter).

typedef _Float16 f16x8 __attribute__((ext_vector_type(8)));
typedef float    f32x4 __attribute__((ext_vector_type(4)));
typedef unsigned long long u64;

#define LROW 2056
#define NBLK 256u

static __device__ __forceinline__ float fast_sig(float x) {
  return 1.f / (1.f + __expf(-x));
}
static __device__ __forceinline__ float fast_tanh(float x) {
  x = fminf(15.f, fmaxf(-15.f, x));
  const float e = __expf(2.f * x);
  return (e - 1.f) / (e + 1.f);
}

static __device__ __forceinline__ void st_h16(void* p, float v) {
  const unsigned short b = __builtin_bit_cast(unsigned short, (_Float16)v);
  __hip_atomic_store((unsigned short*)p, b, __ATOMIC_RELAXED, __HIP_MEMORY_SCOPE_AGENT);
}
static __device__ __forceinline__ void st_h64(void* p, u64 v) {
  __hip_atomic_store((u64*)p, v, __ATOMIC_RELAXED, __HIP_MEMORY_SCOPE_AGENT);
}

// Packed h layout (r4-validated): element (n, j) at byte offset
//   ((n>>4)<<16) + ((j>>5)<<10) + ((n&15)<<6) + (((j>>3)&3)<<4) + ((j&7)<<1)
// Consumer lane (cc,q) reads 16 B contiguous per kc; a wave covers 1 KB/instr.
static __device__ __forceinline__ int h_off(int n, int j) {
  return ((n >> 4) << 16) + ((j >> 5) << 10) + ((n & 15) << 6) +
         (((j >> 3) & 3) << 4) + ((j & 7) << 1);
}

__global__ void __launch_bounds__(256) seq_sum_kernel(const float* __restrict__ X,
                                                      float* s_all) {
  const int gw   = (int)((blockIdx.x * blockDim.x + threadIdx.x) >> 6);
  const int lane = threadIdx.x & 63;
  const int n = gw >> 9, t = gw & 511;
  const float4* p = (const float4*)(X + ((size_t)gw << 10));
  float s = 0.f;
#pragma unroll
  for (int i = 0; i < 4; ++i) {
    const float4 v = p[lane + (i << 6)];
    s += (v.x + v.y) + (v.z + v.w);
  }
#pragma unroll
  for (int off = 32; off; off >>= 1) s += __shfl_xor(s, off);
  if (lane == 0) s_all[(t << 6) + n] = s;
}

__global__ void bar_init_kernel(unsigned* bar) {
  bar[threadIdx.x]       = 0u;
  bar[threadIdx.x + 256] = 0u;
  bar[threadIdx.x + 512] = 0u;
  bar[threadIdx.x + 768] = 0u;
}

// Two-level monotonic grid barrier; all ops relaxed agent-scope (L3-homed).
static __device__ __forceinline__ void grid_barrier2(unsigned* bar, unsigned round,
                                                     int tid, int blk) {
  asm volatile("s_waitcnt vmcnt(0)" ::: "memory");  // write-through stores drained
  __syncthreads();
  if (tid == 0) {
    unsigned* grp  = bar + ((blk & 7) << 5);
    unsigned* root = bar + 512;
    const unsigned old =
        __hip_atomic_fetch_add(grp, 1u, __ATOMIC_RELAXED, __HIP_MEMORY_SCOPE_AGENT);
    if (old == 32u * round - 1u)
      __hip_atomic_fetch_add(root, 1u, __ATOMIC_RELAXED, __HIP_MEMORY_SCOPE_AGENT);
    const unsigned target = 8u * round;
    unsigned guard = 0;
    while (__hip_atomic_load(root, __ATOMIC_RELAXED, __HIP_MEMORY_SCOPE_AGENT) <
           target) {
      __builtin_amdgcn_s_sleep(1);
      if (++guard > (1u << 23)) break;  // anti-hang guard; never fires when resident
    }
  }
  __syncthreads();
}

// Issue 4 sc1 dwordx4 loads from one 4-KB window (one address pair, imm offsets).
#define LOAD4(d0, d1, d2, d3, addr)                                         \
  asm volatile("global_load_dwordx4 %0, %4, off sc1\n\t"                    \
               "global_load_dwordx4 %1, %4, off offset:1024 sc1\n\t"        \
               "global_load_dwordx4 %2, %4, off offset:2048 sc1\n\t"        \
               "global_load_dwordx4 %3, %4, off offset:3072 sc1"            \
               : "=v"(d0), "=v"(d1), "=v"(d2), "=v"(d3)                     \
               : "v"(addr)                                                  \
               : "memory")

// Wait until <= n vmem ops outstanding; ties all 16 fragments of the group so
// dependent MFMAs cannot hoist above; memory clobber pins all other mem ops.
#define WAITG(n, A)                                                         \
  asm volatile("s_waitcnt vmcnt(" #n ")"                                    \
               : "+v"(A[0]), "+v"(A[1]), "+v"(A[2]), "+v"(A[3]),            \
                 "+v"(A[4]), "+v"(A[5]), "+v"(A[6]), "+v"(A[7]),            \
                 "+v"(A[8]), "+v"(A[9]), "+v"(A[10]), "+v"(A[11]),          \
                 "+v"(A[12]), "+v"(A[13]), "+v"(A[14]), "+v"(A[15])         \
               :                                                            \
               : "memory")

__global__ void __launch_bounds__(256, 1) ginv_lstm_persist(
    const float* __restrict__ lin_W, const float* __restrict__ inv_w,
    const float* __restrict__ inv_b, const float* __restrict__ lin_b,
    const float* s_all, const float* __restrict__ H0,
    _Float16* hb0, _Float16* hb1, unsigned* bar, float* out) {
  __shared__ _Float16 Wl[32 * LROW];            // 131584 B -> 1 block/CU
  __shared__ __align__(16) _Float16 hx[64][8];  // 1 KB h transpose buffer
  const int blk = blockIdx.x;
  const int tid = threadIdx.x;
  _Float16* hbuf[2] = {hb0, hb1};

  // ---- stage weight slice fp32 -> fp16 LDS (once) ----
  for (int base = tid * 4; base < 32 * 2048; base += 1024) {
    const int r  = base >> 11;
    const int hc = base & 2047;
    const int g  = r >> 3;
    const int kf = r & 7;
    const float4 v =
        *(const float4*)&lin_W[(((size_t)(g * 2048 + blk * 8 + kf)) << 11) + hc];
    _Float16* d = &Wl[r * LROW + hc];
    d[0] = (_Float16)v.x; d[1] = (_Float16)v.y;
    d[2] = (_Float16)v.z; d[3] = (_Float16)v.w;
  }

  // ---- init h(0) into packed layout (write-through) ----
  {
    int i0 = blk * 512 + tid;
    st_h16((char*)hb0 + h_off(i0 >> 11, i0 & 2047), H0[i0]);
    i0 += 256;
    st_h16((char*)hb0 + h_off(i0 >> 11, i0 & 2047), H0[i0]);
  }

  const int wave = tid >> 6;
  const int lane = tid & 63;
  const int q    = lane >> 4;
  const int cc   = lane & 15;
  const int kf   = cc & 7;
  const int Kg   = blk * 8 + kf;
  const int g0   = (cc < 8) ? 0 : 1;
  const int g1   = (cc < 8) ? 2 : 3;
  const float w0 = inv_w[(g0 << 11) + Kg];
  const float b0 = inv_b[(g0 << 11) + Kg] + lin_b[(g0 << 11) + Kg];
  const float w1 = inv_w[(g1 << 11) + Kg];
  const float b1 = inv_b[(g1 << 11) + Kg] + lin_b[(g1 << 11) + Kg];

  unsigned round = 1;
  grid_barrier2(bar, round, tid, blk);  // h(0) + weights staged grid-wide

  float cst[4] = {0.f, 0.f, 0.f, 0.f};

  const int ld_base = (wave << 16) + (cc << 6) + (q << 4);
  const int lb0 = cc * LROW + q * 8;
  const int lb1 = (16 + cc) * LROW + q * 8;
  const int st_off = ((lane >> 4) << 16) + ((blk >> 2) << 10) + ((lane & 15) << 6) +
                     ((blk & 3) << 4);

  for (int t = 0; t < 512; ++t) {
    const char* hpb = (const char*)hbuf[t & 1] + ld_base;

    // s_all read issued BEFORE the pipeline: an older outstanding vmem op only
    // makes the group waits stricter (never looser).
    const float4 s4 = *(const float4*)&s_all[(t << 6) + wave * 16 + q * 4];

    f16x8 pa[16], pb[16];  // double-buffered prefetch: 32 fragments = 128 VGPRs

    // issue G0 -> pa, G1 -> pb   (16 loads each; 4 addr pairs/group)
#pragma unroll
    for (int w = 0; w < 4; ++w)
      LOAD4(pa[w * 4], pa[w * 4 + 1], pa[w * 4 + 2], pa[w * 4 + 3],
            hpb + (w << 12));
#pragma unroll
    for (int w = 0; w < 4; ++w)
      LOAD4(pb[w * 4], pb[w * 4 + 1], pb[w * 4 + 2], pb[w * 4 + 3],
            hpb + 16384 + (w << 12));

    f32x4 acc0 = {0.f, 0.f, 0.f, 0.f};
    f32x4 acc1 = {0.f, 0.f, 0.f, 0.f};

    auto kmath = [&](const f16x8* A, int gbase) {
#pragma unroll
      for (int i = 0; i < 16; ++i) {
        const int kc = gbase + i;
        const f16x8 bb0 = *(const f16x8*)&Wl[lb0 + kc * 32];   // ds_read_b128
        const f16x8 bb1 = *(const f16x8*)&Wl[lb1 + kc * 32];
        acc0 = __builtin_amdgcn_mfma_f32_16x16x32_f16(A[i], bb0, acc0, 0, 0, 0);
        acc1 = __builtin_amdgcn_mfma_f32_16x16x32_f16(A[i], bb1, acc1, 0, 0, 0);
      }
    };

    WAITG(16, pa);            // G0 landed (G1 = newest 16 may be in flight)
    kmath(pa, 0);
#pragma unroll
    for (int w = 0; w < 4; ++w)  // issue G2 -> pa
      LOAD4(pa[w * 4], pa[w * 4 + 1], pa[w * 4 + 2], pa[w * 4 + 3],
            hpb + 32768 + (w << 12));
    WAITG(16, pb);            // G1 landed
    kmath(pb, 16);
#pragma unroll
    for (int w = 0; w < 4; ++w)  // issue G3 -> pb
      LOAD4(pb[w * 4], pb[w * 4 + 1], pb[w * 4 + 2], pb[w * 4 + 3],
            hpb + 49152 + (w << 12));
    WAITG(16, pa);            // G2 landed
    kmath(pa, 32);
    WAITG(0, pb);             // G3 landed
    kmath(pb, 48);

    // ---- gates.  acc row = batch (q*4+v) within wave tile, col = cc. ----
    const float sv[4] = {s4.x, s4.y, s4.z, s4.w};
    float hnew[4];
#pragma unroll
    for (int v = 0; v < 4; ++v) {
      const float z0 = acc0[v] + sv[v] * w0 + b0;   // cc<8: gate i ; cc>=8: gate f
      const float z1 = acc1[v] + sv[v] * w1 + b1;   // cc<8: gate g ; cc>=8: gate o
      const float zf = __shfl_xor(z0, 8);
      const float zo = __shfl_xor(z1, 8);
      const float ig = fast_sig(z0);
      const float fg = fast_sig(zf);
      const float gg = fast_tanh(z1);
      const float og = fast_sig(zo);
      const float cn = fg * cst[v] + ig * gg;
      cst[v] = cn;
      hnew[v] = og * fast_tanh(cn);
    }

    // Transpose block's h slice through LDS (also at t=511, feeds the epilogue).
    if (cc < 8) {
#pragma unroll
      for (int v = 0; v < 4; ++v)
        hx[(wave << 4) + (q << 2) + v][cc] = (_Float16)hnew[v];
    }
    __syncthreads();
    if (t < 511 && tid < 64) {
      union { f16x8 v; u64 w[2]; } u;
      u.v = *(const f16x8*)hx[lane];
      char* dst = (char*)hbuf[(t + 1) & 1] + st_off;
      st_h64(dst, u.w[0]);
      st_h64(dst + 8, u.w[1]);
    }
    ++round;
    grid_barrier2(bar, round, tid, blk);  // also orders s_all reads vs out (fallback)
  }

  // Epilogue: hx holds h(511); lane = batch row, features blk*8..blk*8+7.
  if (tid < 64) {
    const f16x8 hv = *(const f16x8*)hx[lane];
#pragma unroll
    for (int f = 0; f < 8; ++f)
      out[((blk * 8 + f) << 6) + lane] = (float)hv[f];
  }
}

extern "C" void kernel_launch(void* const* d_in, const int* in_sizes, int n_in,
                              void* d_out, int out_size, void* d_ws, size_t ws_size,
                              hipStream_t stream) {
  const float* X     = (const float*)d_in[0];
  const float* H0    = (const float*)d_in[1];
  const float* inv_w = (const float*)d_in[2];
  const float* inv_b = (const float*)d_in[3];
  const float* lin_W = (const float*)d_in[4];
  const float* lin_b = (const float*)d_in[5];
  float* out = (float*)d_out;

  const size_t S_BYTES = 512 * 64 * 4;
  const size_t BAR_PAD = 4096;
  const size_t H_BYTES = 64 * 2048 * 2;
  const size_t NEED = S_BYTES + BAR_PAD + 2 * H_BYTES;

  float*    s_all;
  unsigned* bar;
  _Float16* hb[2];
  if (ws_size >= NEED) {
    char* ws = (char*)d_ws;
    s_all = (float*)ws;
    bar   = (unsigned*)(ws + S_BYTES);
    for (int i = 0; i < 2; ++i)
      hb[i] = (_Float16*)(ws + S_BYTES + BAR_PAD + (size_t)i * H_BYTES);
  } else {
    // Fallback: s_all in d_out (final out written after last barrier), bar + h
    // buffers in X's tail (X fully consumed by seq_sum_kernel first on-stream;
    // harness restores X before every launch).
    s_all = (float*)d_out;
    char* xt = (char*)d_in[0] + (size_t)64 * 512 * 1024 * 4 -
               (BAR_PAD + 2 * H_BYTES);
    bar = (unsigned*)xt;
    for (int i = 0; i < 2; ++i)
      hb[i] = (_Float16*)(xt + BAR_PAD + (size_t)i * H_BYTES);
  }

  seq_sum_kernel<<<8192, 256, 0, stream>>>(X, s_all);
  bar_init_kernel<<<1, 256, 0, stream>>>(bar);
  ginv_lstm_persist<<<256, 256, 0, stream>>>(lin_W, inv_w, inv_b, lin_b, s_all, H0,
                                             hb[0], hb[1], bar, out);
}